// Round 12
// baseline (279.074 us; speedup 1.0000x reference)
//
#include <hip/hip_runtime.h>
#include <hip/hip_bf16.h>

// TransitionGNN fused pipeline, r12.
// Single change vs r11: the edge A-build's VALU diet.
//  - PQ is now stored fp32 (combo writes raw floats; no convert in epilogue),
//    killing the 8 bf16->f32 up-shifts per 4 elements in edge buildA.
//  - buildA packs relu(P+Q) via v_perm_b32 (__builtin_amdgcn_perm): 1 inst
//    packs 2 fp32 high-halves = 2 bf16 RTZ converts. Build cost per 4 elems:
//    4 add + 4 max + 2 perm (~10 VALU) vs ~30 before. RTZ only touches h1
//    (post-relu >= 0, next op is LN) — absmax predicted <= 0.02 (thr 0.033).
// Rationale: r4/r6/r10/r11 all pin edge at 119-121us, MfmaUtil 24%, VALU 50%,
// occupancy hard-capped at 4 waves/SIMD (64 acc regs forced by 512-col LN
// tile) -> only lever left is shrinking the non-MFMA instruction stream.

using bf16 = __hip_bfloat16;
typedef __attribute__((ext_vector_type(8))) short bf16x8;
typedef __attribute__((ext_vector_type(4))) short short4v;
typedef __attribute__((ext_vector_type(4))) float f32x4;

#define LDK 40   // LDS row stride (32 + 8 pad) for GEMM staging tiles
#define LDN 520  // 512-col activation tile stride
#define LDT 72   // mega_prep 64-col tile stride (64 + 8 pad)

__device__ __forceinline__ short f2bf(float f) {
  bf16 h = __float2bfloat16(f);
  return *reinterpret_cast<short*>(&h);
}
__device__ __forceinline__ float bs2f(short s) {
  bf16 h = *reinterpret_cast<bf16*>(&s);
  return __bfloat162float(h);
}
__device__ __forceinline__ f32x4 mfma16(bf16x8 a, bf16x8 b, f32x4 c) {
  return __builtin_amdgcn_mfma_f32_16x16x32_bf16(a, b, c, 0, 0, 0);
}
// pack 2 fp32 -> 2 bf16 (RTZ) in one v_perm_b32: low16=bf16(lo), high16=bf16(hi)
__device__ __forceinline__ unsigned int pk2bf_rtz(float lo, float hi) {
  unsigned int a = __builtin_bit_cast(unsigned int, lo);
  unsigned int b = __builtin_bit_cast(unsigned int, hi);
  return __builtin_amdgcn_perm(b, a, 0x07060302u);  // bytes: [a2,a3,b2,b3]
}
// load 8 consecutive fp32 -> bf16x8 (32B-aligned source)
__device__ __forceinline__ bf16x8 ld8f(const float* p) {
  float4 a = *(const float4*)p;
  float4 b = *(const float4*)(p + 4);
  bf16x8 o;
  o[0] = f2bf(a.x); o[1] = f2bf(a.y); o[2] = f2bf(a.z); o[3] = f2bf(a.w);
  o[4] = f2bf(b.x); o[5] = f2bf(b.y); o[6] = f2bf(b.z); o[7] = f2bf(b.w);
  return o;
}

// ---------------------------------------------------------------- mega_prep
// z=0: eW3 fp32->bf16 cvt [256 blk]; z=1: nW1_agg transpose [256 blk];
// z=2..7: frag-layout swizzles via 32x64 LDS tile (coalesced read+write).
__global__ __launch_bounds__(256) void mega_prep(
    const float* __restrict__ eW3, short* __restrict__ eW3b,
    const float* __restrict__ nW1, unsigned short* __restrict__ nW1at,
    const float* __restrict__ eW1, short* __restrict__ eW1f,
    const float* __restrict__ eW2, short* __restrict__ eW2f,
    short* __restrict__ nW1nf, const float* __restrict__ nW2,
    short* __restrict__ nW2f, const float* __restrict__ nW3,
    short* __restrict__ nW3f) {
  __shared__ unsigned short ttile[32][33];
  __shared__ short ftile[32 * LDT];
  const int z = blockIdx.z, bx = blockIdx.x, t = threadIdx.x;
  if (z == 0) {
    if (bx >= 256) return;
    int i = (bx * 256 + t) * 4;
    float4 v = *(const float4*)(eW3 + i);
    short4v o;
    o.x = f2bf(v.x); o.y = f2bf(v.y); o.z = f2bf(v.z); o.w = f2bf(v.w);
    *(short4v*)(eW3b + i) = o;
    return;
  }
  if (z == 1) {
    if (bx >= 256) return;
    const float* src = nW1 + 132 * 512;
    int bc = (bx & 15) * 32, br = (bx >> 4) * 32;
    int tx = t & 31, ty = t >> 5;
    for (int i = ty; i < 32; i += 8) {
      short s = f2bf(src[(size_t)(br + i) * 512 + bc + tx]);
      ttile[i][tx] = *reinterpret_cast<unsigned short*>(&s);
    }
    __syncthreads();
    for (int i = ty; i < 32; i += 8)
      nW1at[(size_t)(bc + i) * 512 + br + tx] = ttile[tx][i];
    return;
  }
  const float* W;
  short* out;
  int ldw, kts, gq, goff, tot_sh;
  switch (z) {
    case 2: W = eW1;           out = eW1f;  ldw = 512; kts = 4;  gq = 8; goff = 0;  tot_sh = 6; break;
    case 3: W = eW1 + 128*512; out = eW1f;  ldw = 512; kts = 4;  gq = 8; goff = 32; tot_sh = 6; break;
    case 4: W = eW2;           out = eW2f;  ldw = 512; kts = 16; gq = 8; goff = 0;  tot_sh = 5; break;
    case 5: W = nW1;           out = nW1nf; ldw = 512; kts = 4;  gq = 8; goff = 0;  tot_sh = 5; break;
    case 6: W = nW2;           out = nW2f;  ldw = 512; kts = 16; gq = 8; goff = 0;  tot_sh = 5; break;
    default: W = nW3;          out = nW3f;  ldw = 128; kts = 16; gq = 2; goff = 0;  tot_sh = 3; break;
  }
  if (bx >= kts * gq) return;
  const int kt = bx / gq, qg = bx % gq;
  {
    int r = t >> 3, c0 = (t & 7) * 8;
    const float* src = W + (size_t)(kt * 32 + r) * ldw + qg * 64 + c0;
    *(bf16x8*)&ftile[r * LDT + c0] = ld8f(src);
  }
  __syncthreads();
  {
    int og = t >> 6, lane = t & 63, q = lane >> 4, lc = lane & 15;
    int gg = qg * 4 + og;
    size_t base = ((size_t)((kt << tot_sh) + gg + goff)) << 9;
    bf16x8 v;
#pragma unroll
    for (int j = 0; j < 8; ++j) v[j] = ftile[(q * 8 + j) * LDT + og * 16 + lc];
    *(bf16x8*)(out + base + lane * 8) = v;
  }
}

// ---------------------------------------------------------------- combo
// blocks 0..63: Wc frag tiles; 64..95: bias fold; 96..607: PQ gemm -> fp32.
__global__ __launch_bounds__(256) void combo(
    const bf16* __restrict__ nW1at, const bf16* __restrict__ eW3b,
    short* __restrict__ Wcf, const float* __restrict__ eb3,
    const float* __restrict__ nb1, const float* __restrict__ nW1,
    float* __restrict__ bfold, const float* __restrict__ states,
    const bf16* __restrict__ eW1f, const float* __restrict__ eb1,
    float* __restrict__ PQf) {
  __shared__ short Al[64 * LDK];
  __shared__ short Bl[64 * LDK];
  __shared__ float red[256];
  __shared__ short sts[16 * 136];
  const int bid = blockIdx.x;
  const int t = threadIdx.x;
  const int wid = t >> 6, lane = t & 63, q = lane >> 4, lc = lane & 15;
  const f32x4 zz = {0.f, 0.f, 0.f, 0.f};

  if (bid < 64) {  // ---- Wc tile (64x64), K=512
    const int wm = wid >> 1, wn = wid & 1;
    const int n0 = (bid >> 3) * 64, k0 = (bid & 7) * 64;
    f32x4 acc[2][2];
#pragma unroll
    for (int mb = 0; mb < 2; ++mb)
#pragma unroll
      for (int nb = 0; nb < 2; ++nb) acc[mb][nb] = zz;
    const int sr = t >> 2, seg = t & 3;
    for (int h0 = 0; h0 < 512; h0 += 32) {
      *(uint4*)&Al[sr * LDK + seg * 8] =
          *(const uint4*)(nW1at + (size_t)(n0 + sr) * 512 + h0 + seg * 8);
      *(uint4*)&Bl[sr * LDK + seg * 8] =
          *(const uint4*)(eW3b + (size_t)(k0 + sr) * 512 + h0 + seg * 8);
      __syncthreads();
      bf16x8 af[2], bfr[2];
#pragma unroll
      for (int mb = 0; mb < 2; ++mb)
        af[mb] = *(const bf16x8*)&Al[(wm * 32 + mb * 16 + lc) * LDK + q * 8];
#pragma unroll
      for (int nb = 0; nb < 2; ++nb)
        bfr[nb] = *(const bf16x8*)&Bl[(wn * 32 + nb * 16 + lc) * LDK + q * 8];
#pragma unroll
      for (int mb = 0; mb < 2; ++mb)
#pragma unroll
        for (int nb = 0; nb < 2; ++nb)
          acc[mb][nb] = mfma16(af[mb], bfr[nb], acc[mb][nb]);
      __syncthreads();
    }
#pragma unroll
    for (int mb = 0; mb < 2; ++mb)
#pragma unroll
      for (int nb = 0; nb < 2; ++nb)
#pragma unroll
        for (int r = 0; r < 4; ++r) {
          int n = n0 + wm * 32 + mb * 16 + q * 4 + r;
          int k = k0 + wn * 32 + nb * 16 + lc;
          int kt = k >> 5, kin = k & 31, qf = kin >> 3, jf = kin & 7;
          Wcf[(((size_t)kt * 32 + (n >> 4)) * 64 + qf * 16 + (n & 15)) * 8 +
              jf] = f2bf(acc[mb][nb][r]);
        }
    return;
  }
  if (bid < 96) {  // ---- bias fold, 32-way parallel
    const int n = (bid - 64) * 16 + (t & 15);
    const int sl = t >> 4;
    float s = 0.f;
#pragma unroll 8
    for (int h = sl * 32; h < sl * 32 + 32; ++h)
      s += eb3[h] * nW1[(size_t)(132 + h) * 512 + n];
    red[sl * 16 + (t & 15)] = s;
    __syncthreads();
    if (t < 16) {
      float tot = 0.f;
#pragma unroll
      for (int k = 0; k < 16; ++k) tot += red[k * 16 + t];
      bfold[(bid - 64) * 16 + t] = nb1[(bid - 64) * 16 + t] + 15.f * tot;
    }
    return;
  }
  // ---- PQ gemm: 16-row tile, K=128, N=1024; fp32 OUTPUT (no convert)
  const int m0 = (bid - 96) * 16;
  {
    int r = t >> 4, c8 = (t & 15) * 8;
    *(bf16x8*)&sts[r * 136 + c8] = ld8f(states + (size_t)(m0 + r) * 128 + c8);
  }
  __syncthreads();
  f32x4 acc[16];
#pragma unroll
  for (int nb = 0; nb < 16; ++nb) acc[nb] = zz;
#pragma unroll
  for (int kt = 0; kt < 4; ++kt) {
    bf16x8 af = *(const bf16x8*)&sts[lc * 136 + kt * 32 + q * 8];
#pragma unroll
    for (int nb = 0; nb < 16; ++nb) {
      bf16x8 bfr = *(const bf16x8*)(eW1f +
                                    (((size_t)kt * 64 + wid * 16 + nb) * 64 +
                                     lane) * 8);
      acc[nb] = mfma16(af, bfr, acc[nb]);
    }
  }
#pragma unroll
  for (int nb = 0; nb < 16; ++nb) {
    int col = wid * 256 + nb * 16 + lc;
    float bv = (col < 512) ? eb1[col] : 0.f;
#pragma unroll
    for (int r = 0; r < 4; ++r)
      PQf[(size_t)(m0 + q * 4 + r) * 1024 + col] = acc[nb][r] + bv;
  }
}

// ---------------------------------------------------------------- edge v7
// r6 dbuf structure; buildA reads fp32 PQ and packs via v_perm (RTZ):
// per 4 elems: 4 add + 4 max + 2 perm (~10 VALU, was ~30).
__global__ __launch_bounds__(512, 4) void edge_ln_seg7(
    const float* __restrict__ PQf, const bf16* __restrict__ Wf,
    const float* __restrict__ b2, const float* __restrict__ g,
    const float* __restrict__ be, bf16* __restrict__ S) {
  __shared__ short Alds[2][64 * LDK];
  __shared__ float s_sum[64 * 8];
  __shared__ float s_sq[64 * 8];
  const int t = threadIdx.x;
  const int w = t >> 6, lane = t & 63, q = lane >> 4, lc = lane & 15;
  const int g0 = blockIdx.x * 4;
  const int bb = g0 >> 4;
  const f32x4 zz = {0.f, 0.f, 0.f, 0.f};
  f32x4 acc[4][4];
#pragma unroll
  for (int mb = 0; mb < 4; ++mb)
#pragma unroll
    for (int nb = 0; nb < 4; ++nb) acc[mb][nb] = zz;

  const int ar = t >> 3;
  const int kk = (t & 7) * 4;
  const int gA = ar >> 4;
  const int slot = ar & 15;
  const int aiA = (g0 & 15) + gA;
  const bool padA = (slot == 15);
  const int dstA = padA ? 0 : slot + (slot >= aiA ? 1 : 0);
  const float* pA = PQf + (size_t)(g0 + gA) * 1024 + kk;
  const float* qA = PQf + (size_t)(bb * 16 + dstA) * 1024 + 512 + kk;

  auto buildA = [&](int kt, int buf) {
    unsigned int lo = 0, hi = 0;
    if (!padA) {
      float4 pv = *(const float4*)(pA + kt * 32);
      float4 qv = *(const float4*)(qA + kt * 32);
      float x0 = fmaxf(pv.x + qv.x, 0.f);
      float x1 = fmaxf(pv.y + qv.y, 0.f);
      float x2 = fmaxf(pv.z + qv.z, 0.f);
      float x3 = fmaxf(pv.w + qv.w, 0.f);
      lo = pk2bf_rtz(x0, x1);
      hi = pk2bf_rtz(x2, x3);
    }
    uint2 v = {lo, hi};
    *(uint2*)&Alds[buf][ar * LDK + kk] = v;
  };

  buildA(0, 0);
#pragma unroll 1
  for (int kt = 0; kt < 16; ++kt) {
    __syncthreads();
    const int cur = kt & 1;
    bf16x8 bfr[4], af[4];
#pragma unroll
    for (int nb = 0; nb < 4; ++nb)
      bfr[nb] = *(const bf16x8*)(Wf +
                                 (((size_t)kt * 32 + w * 4 + nb) * 64 + lane) * 8);
#pragma unroll
    for (int mb = 0; mb < 4; ++mb)
      af[mb] = *(const bf16x8*)&Alds[cur][(mb * 16 + lc) * LDK + q * 8];
    if (kt < 15) buildA(kt + 1, cur ^ 1);
#pragma unroll
    for (int mb = 0; mb < 4; ++mb)
#pragma unroll
      for (int nb = 0; nb < 4; ++nb)
        acc[mb][nb] = mfma16(af[mb], bfr[nb], acc[mb][nb]);
  }

  float bv[4], gv[4], bev[4];
#pragma unroll
  for (int nb = 0; nb < 4; ++nb) {
    int col = w * 64 + nb * 16 + lc;
    bv[nb] = b2[col];
    gv[nb] = g[col];
    bev[nb] = be[col];
  }
#pragma unroll
  for (int mb = 0; mb < 4; ++mb)
#pragma unroll
    for (int nb = 0; nb < 4; ++nb)
#pragma unroll
      for (int r = 0; r < 4; ++r) acc[mb][nb][r] += bv[nb];

#pragma unroll
  for (int mb = 0; mb < 4; ++mb) {
    float ps[4] = {0, 0, 0, 0}, pq2[4] = {0, 0, 0, 0};
#pragma unroll
    for (int nb = 0; nb < 4; ++nb)
#pragma unroll
      for (int r = 0; r < 4; ++r) {
        float x = acc[mb][nb][r];
        ps[r] += x;
        pq2[r] += x * x;
      }
#pragma unroll
    for (int d = 1; d < 16; d <<= 1)
#pragma unroll
      for (int r = 0; r < 4; ++r) {
        ps[r] += __shfl_xor(ps[r], d, 64);
        pq2[r] += __shfl_xor(pq2[r], d, 64);
      }
    if (lc == 0)
#pragma unroll
      for (int r = 0; r < 4; ++r) {
        int row = mb * 16 + q * 4 + r;
        s_sum[row * 8 + w] = ps[r];
        s_sq[row * 8 + w] = pq2[r];
      }
  }
  __syncthreads();
#pragma unroll
  for (int mb = 0; mb < 4; ++mb) {
    float sv[4] = {0, 0, 0, 0};
#pragma unroll
    for (int r = 0; r < 4; ++r) {
      int row = mb * 16 + q * 4 + r;
      float tot = 0.f, tsq = 0.f;
#pragma unroll
      for (int wv = 0; wv < 8; ++wv) {
        tot += s_sum[row * 8 + wv];
        tsq += s_sq[row * 8 + wv];
      }
      float m = tot * (1.f / 512.f);
      float rstd = rsqrtf(tsq * (1.f / 512.f) - m * m + 1e-5f);
#pragma unroll
      for (int nb = 0; nb < 4; ++nb) {
        float h = (acc[mb][nb][r] - m) * rstd * gv[nb] + bev[nb];
        h = fmaxf(h, 0.f);
        if (q * 4 + r != 15) sv[nb] += h;
      }
    }
#pragma unroll
    for (int nb = 0; nb < 4; ++nb) {
      sv[nb] += __shfl_xor(sv[nb], 16, 64);
      sv[nb] += __shfl_xor(sv[nb], 32, 64);
    }
    if (lane < 16)
#pragma unroll
      for (int nb = 0; nb < 4; ++nb)
        S[(size_t)(g0 + mb) * 512 + w * 64 + nb * 16 + lc] =
            __float2bfloat16(sv[nb]);
  }
}

// ---------------------------------------------------------------- node_fused
// unchanged from r11 (LDS-staged A-tiles).
__global__ __launch_bounds__(256) void node_fused(
    const float* __restrict__ states, const bf16* __restrict__ S,
    const bf16* __restrict__ nW1nf, const bf16* __restrict__ Wcf,
    const bf16* __restrict__ nW2f, const bf16* __restrict__ nW3f,
    const float* __restrict__ bfold, const int* __restrict__ action,
    const float* __restrict__ nW1, const float* __restrict__ nb2,
    const float* __restrict__ ng, const float* __restrict__ nbt,
    const float* __restrict__ nb3, float* __restrict__ Out) {
  __shared__ short sts[16 * 136];
  __shared__ short Ss[16 * LDN];
  __shared__ short n1s[16 * LDN];
  __shared__ float s_sum[16 * 4];
  __shared__ float s_sq[16 * 4];
  const int t = threadIdx.x;
  const int wid = t >> 6, lane = t & 63, q = lane >> 4, lc = lane & 15;
  const int m0 = blockIdx.x * 16;
  const f32x4 zz = {0.f, 0.f, 0.f, 0.f};

  {
    int r = t >> 4, c8 = (t & 15) * 8;
    *(bf16x8*)&sts[r * 136 + c8] = ld8f(states + (size_t)(m0 + r) * 128 + c8);
    int sgi = t & 15;
#pragma unroll
    for (int it = 0; it < 4; ++it) {
      int seg = sgi + it * 16;
      *(uint4*)&Ss[r * LDN + seg * 8] =
          *(const uint4*)(S + (size_t)(m0 + r) * 512 + seg * 8);
    }
  }
  __syncthreads();

  f32x4 acc[8];
#pragma unroll
  for (int nb = 0; nb < 8; ++nb) acc[nb] = zz;
#pragma unroll
  for (int kt = 0; kt < 4; ++kt) {
    bf16x8 af = *(const bf16x8*)&sts[lc * 136 + kt * 32 + q * 8];
#pragma unroll
    for (int nb = 0; nb < 8; ++nb) {
      bf16x8 bfr = *(const bf16x8*)(nW1nf +
                                    (((size_t)kt * 32 + wid * 8 + nb) * 64 +
                                     lane) * 8);
      acc[nb] = mfma16(af, bfr, acc[nb]);
    }
  }
#pragma unroll 2
  for (int kt = 0; kt < 16; ++kt) {
    bf16x8 af = *(const bf16x8*)&Ss[lc * LDN + kt * 32 + q * 8];
#pragma unroll
    for (int nb = 0; nb < 8; ++nb) {
      bf16x8 bfr = *(const bf16x8*)(Wcf +
                                    (((size_t)kt * 32 + wid * 8 + nb) * 64 +
                                     lane) * 8);
      acc[nb] = mfma16(af, bfr, acc[nb]);
    }
  }
  {
    int a = action[m0 >> 4];
    int aw = a >> 2, ac4 = a & 3;
#pragma unroll
    for (int nb = 0; nb < 8; ++nb) {
      int col = wid * 128 + nb * 16 + lc;
      float bv = bfold[col];
      float awv = nW1[(size_t)(128 + ac4) * 512 + col];
#pragma unroll
      for (int r = 0; r < 4; ++r) {
        int row = q * 4 + r;
        float x = acc[nb][r] + bv + (row == aw ? awv : 0.f);
        n1s[row * LDN + col] = f2bf(fmaxf(x, 0.f));
      }
    }
  }
  __syncthreads();

  f32x4 acc2[8];
#pragma unroll
  for (int nb = 0; nb < 8; ++nb) acc2[nb] = zz;
#pragma unroll 2
  for (int kt = 0; kt < 16; ++kt) {
    bf16x8 af = *(const bf16x8*)&n1s[lc * LDN + kt * 32 + q * 8];
#pragma unroll
    for (int nb = 0; nb < 8; ++nb) {
      bf16x8 bfr = *(const bf16x8*)(nW2f +
                                    (((size_t)kt * 32 + wid * 8 + nb) * 64 +
                                     lane) * 8);
      acc2[nb] = mfma16(af, bfr, acc2[nb]);
    }
  }
  float gv[8], bev[8];
  {
    float ps[4] = {0, 0, 0, 0}, pq2[4] = {0, 0, 0, 0};
#pragma unroll
    for (int nb = 0; nb < 8; ++nb) {
      int col = wid * 128 + nb * 16 + lc;
      float bv = nb2[col];
      gv[nb] = ng[col];
      bev[nb] = nbt[col];
#pragma unroll
      for (int r = 0; r < 4; ++r) {
        acc2[nb][r] += bv;
        ps[r] += acc2[nb][r];
        pq2[r] += acc2[nb][r] * acc2[nb][r];
      }
    }
#pragma unroll
    for (int d = 1; d < 16; d <<= 1)
#pragma unroll
      for (int r = 0; r < 4; ++r) {
        ps[r] += __shfl_xor(ps[r], d, 64);
        pq2[r] += __shfl_xor(pq2[r], d, 64);
      }
    if (lc == 0)
#pragma unroll
      for (int r = 0; r < 4; ++r) {
        s_sum[(q * 4 + r) * 4 + wid] = ps[r];
        s_sq[(q * 4 + r) * 4 + wid] = pq2[r];
      }
  }
  __syncthreads();
#pragma unroll
  for (int r = 0; r < 4; ++r) {
    int row = q * 4 + r;
    float tot = 0.f, tsq = 0.f;
#pragma unroll
    for (int wv = 0; wv < 4; ++wv) {
      tot += s_sum[row * 4 + wv];
      tsq += s_sq[row * 4 + wv];
    }
    float m = tot * (1.f / 512.f);
    float rstd = rsqrtf(tsq * (1.f / 512.f) - m * m + 1e-5f);
#pragma unroll
    for (int nb = 0; nb < 8; ++nb) {
      int col = wid * 128 + nb * 16 + lc;
      float h = (acc2[nb][r] - m) * rstd * gv[nb] + bev[nb];
      n1s[row * LDN + col] = f2bf(fmaxf(h, 0.f));
    }
  }
  __syncthreads();

  f32x4 acc3[2];
#pragma unroll
  for (int nb = 0; nb < 2; ++nb) acc3[nb] = zz;
#pragma unroll 2
  for (int kt = 0; kt < 16; ++kt) {
    bf16x8 af = *(const bf16x8*)&n1s[lc * LDN + kt * 32 + q * 8];
#pragma unroll
    for (int nb = 0; nb < 2; ++nb) {
      bf16x8 bfr = *(const bf16x8*)(nW3f +
                                    (((size_t)kt * 8 + wid * 2 + nb) * 64 +
                                     lane) * 8);
      acc3[nb] = mfma16(af, bfr, acc3[nb]);
    }
  }
#pragma unroll
  for (int nb = 0; nb < 2; ++nb) {
    int col = wid * 32 + nb * 16 + lc;
    float b3 = nb3[col];
#pragma unroll
    for (int r = 0; r < 4; ++r)
      Out[(size_t)(m0 + q * 4 + r) * 128 + col] = acc3[nb][r] + b3;
  }
}

// ---------------------------------------------------------------- launch
extern "C" void kernel_launch(void* const* d_in, const int* in_sizes, int n_in,
                              void* d_out, int out_size, void* d_ws,
                              size_t ws_size, hipStream_t stream) {
  const float* states = (const float*)d_in[0];
  const int* action = (const int*)d_in[1];
  const float* eW1 = (const float*)d_in[2];
  const float* eb1 = (const float*)d_in[3];
  const float* eW2 = (const float*)d_in[4];
  const float* eb2 = (const float*)d_in[5];
  const float* eg = (const float*)d_in[6];
  const float* ebt = (const float*)d_in[7];
  const float* eW3 = (const float*)d_in[8];
  const float* eb3 = (const float*)d_in[9];
  const float* nW1 = (const float*)d_in[10];
  const float* nb1 = (const float*)d_in[11];
  const float* nW2 = (const float*)d_in[12];
  const float* nb2 = (const float*)d_in[13];
  const float* ng = (const float*)d_in[14];
  const float* nbt = (const float*)d_in[15];
  const float* nW3 = (const float*)d_in[16];
  const float* nb3 = (const float*)d_in[17];

  // ---- workspace (~43.3 MB)
  char* w = (char*)d_ws;
  bf16* eW1f = (bf16*)w;     w += (size_t)131072 * 2;
  bf16* eW2f = (bf16*)w;     w += (size_t)262144 * 2;
  bf16* nW1nf = (bf16*)w;    w += (size_t)65536 * 2;
  bf16* nW2f = (bf16*)w;     w += (size_t)262144 * 2;
  bf16* nW3f = (bf16*)w;     w += (size_t)65536 * 2;
  bf16* Wcf = (bf16*)w;      w += (size_t)262144 * 2;
  bf16* eW3b = (bf16*)w;     w += (size_t)262144 * 2;
  bf16* nW1at = (bf16*)w;    w += (size_t)262144 * 2;
  float* bfold = (float*)w;  w += (size_t)512 * 4;
  float* PQf = (float*)w;    w += (size_t)8192 * 1024 * 4;  // fp32 now
  bf16* S = (bf16*)w;        w += (size_t)8192 * 512 * 2;

  mega_prep<<<dim3(256, 1, 8), 256, 0, stream>>>(
      eW3, (short*)eW3b, nW1, (unsigned short*)nW1at, eW1, (short*)eW1f, eW2,
      (short*)eW2f, (short*)nW1nf, nW2, (short*)nW2f, nW3, (short*)nW3f);

  combo<<<608, 256, 0, stream>>>(nW1at, eW3b, (short*)Wcf, eb3, nb1, nW1,
                                 bfold, states, eW1f, eb1, PQf);

  edge_ln_seg7<<<2048, 512, 0, stream>>>(PQf, eW2f, eb2, eg, ebt, S);

  node_fused<<<512, 256, 0, stream>>>(states, S, nW1nf, Wcf, nW2f, nW3f,
                                      bfold, action, nW1, nb2, ng, nbt, nb3,
                                      (float*)d_out);

  (void)in_sizes; (void)n_in; (void)out_size; (void)ws_size;
}

// Round 13
// 249.782 us; speedup vs baseline: 1.1173x; 1.1173x over previous
//
#include <hip/hip_runtime.h>
#include <hip/hip_bf16.h>

// TransitionGNN fused pipeline, r13.
// Structural: the post-weight pipeline is BATCH-LOCAL (PQ, edges, segment-sum,
// node MLP never cross batches). mega kernel = 1 block per batch (512 blk x
// 512 thr = exactly 2 blocks/CU, one scheduling round): PQ gemm -> 4 edge
// tiles (r6's proven dbuf core) -> node MLP -> out, ALL intermediates in LDS
// (64,000 B static, overlaid). Kills PQ (33MB) + S (8MB) global round-trips
// and 2 kernel-boundary drains that made the old tail ~163us.
// Launches: mega_prep (weight swizzles) -> combo96 (Wc + bias fold) -> mega.

using bf16 = __hip_bfloat16;
typedef __attribute__((ext_vector_type(8))) short bf16x8;
typedef __attribute__((ext_vector_type(4))) short short4v;
typedef __attribute__((ext_vector_type(4))) float f32x4;

#define LDK 40    // A-tile row stride (32 + 8 pad)
#define LDQ 1032  // PQ LDS row stride in shorts (1024 + 8)
#define LDN 520   // 512-col activation row stride
#define LDT 72    // mega_prep tile stride

__device__ __forceinline__ short f2bf(float f) {
  bf16 h = __float2bfloat16(f);
  return *reinterpret_cast<short*>(&h);
}
__device__ __forceinline__ float bs2f(short s) {
  bf16 h = *reinterpret_cast<bf16*>(&s);
  return __bfloat162float(h);
}
__device__ __forceinline__ f32x4 mfma16(bf16x8 a, bf16x8 b, f32x4 c) {
  return __builtin_amdgcn_mfma_f32_16x16x32_bf16(a, b, c, 0, 0, 0);
}
__device__ __forceinline__ bf16x8 ld8f(const float* p) {
  float4 a = *(const float4*)p;
  float4 b = *(const float4*)(p + 4);
  bf16x8 o;
  o[0] = f2bf(a.x); o[1] = f2bf(a.y); o[2] = f2bf(a.z); o[3] = f2bf(a.w);
  o[4] = f2bf(b.x); o[5] = f2bf(b.y); o[6] = f2bf(b.z); o[7] = f2bf(b.w);
  return o;
}

// ---------------------------------------------------------------- mega_prep
// z=0: eW3 fp32->bf16; z=1: nW1_agg transpose; z=2..7: frag swizzles.
__global__ __launch_bounds__(256) void mega_prep(
    const float* __restrict__ eW3, short* __restrict__ eW3b,
    const float* __restrict__ nW1, unsigned short* __restrict__ nW1at,
    const float* __restrict__ eW1, short* __restrict__ eW1f,
    const float* __restrict__ eW2, short* __restrict__ eW2f,
    short* __restrict__ nW1nf, const float* __restrict__ nW2,
    short* __restrict__ nW2f, const float* __restrict__ nW3,
    short* __restrict__ nW3f) {
  __shared__ unsigned short ttile[32][33];
  __shared__ short ftile[32 * LDT];
  const int z = blockIdx.z, bx = blockIdx.x, t = threadIdx.x;
  if (z == 0) {
    if (bx >= 256) return;
    int i = (bx * 256 + t) * 4;
    float4 v = *(const float4*)(eW3 + i);
    short4v o;
    o.x = f2bf(v.x); o.y = f2bf(v.y); o.z = f2bf(v.z); o.w = f2bf(v.w);
    *(short4v*)(eW3b + i) = o;
    return;
  }
  if (z == 1) {
    if (bx >= 256) return;
    const float* src = nW1 + 132 * 512;
    int bc = (bx & 15) * 32, br = (bx >> 4) * 32;
    int tx = t & 31, ty = t >> 5;
    for (int i = ty; i < 32; i += 8) {
      short s = f2bf(src[(size_t)(br + i) * 512 + bc + tx]);
      ttile[i][tx] = *reinterpret_cast<unsigned short*>(&s);
    }
    __syncthreads();
    for (int i = ty; i < 32; i += 8)
      nW1at[(size_t)(bc + i) * 512 + br + tx] = ttile[tx][i];
    return;
  }
  const float* W;
  short* out;
  int ldw, kts, gq, goff, tot_sh;
  switch (z) {
    case 2: W = eW1;           out = eW1f;  ldw = 512; kts = 4;  gq = 8; goff = 0;  tot_sh = 6; break;
    case 3: W = eW1 + 128*512; out = eW1f;  ldw = 512; kts = 4;  gq = 8; goff = 32; tot_sh = 6; break;
    case 4: W = eW2;           out = eW2f;  ldw = 512; kts = 16; gq = 8; goff = 0;  tot_sh = 5; break;
    case 5: W = nW1;           out = nW1nf; ldw = 512; kts = 4;  gq = 8; goff = 0;  tot_sh = 5; break;
    case 6: W = nW2;           out = nW2f;  ldw = 512; kts = 16; gq = 8; goff = 0;  tot_sh = 5; break;
    default: W = nW3;          out = nW3f;  ldw = 128; kts = 16; gq = 2; goff = 0;  tot_sh = 3; break;
  }
  if (bx >= kts * gq) return;
  const int kt = bx / gq, qg = bx % gq;
  {
    int r = t >> 3, c0 = (t & 7) * 8;
    const float* src = W + (size_t)(kt * 32 + r) * ldw + qg * 64 + c0;
    *(bf16x8*)&ftile[r * LDT + c0] = ld8f(src);
  }
  __syncthreads();
  {
    int og = t >> 6, lane = t & 63, q = lane >> 4, lc = lane & 15;
    int gg = qg * 4 + og;
    size_t base = ((size_t)((kt << tot_sh) + gg + goff)) << 9;
    bf16x8 v;
#pragma unroll
    for (int j = 0; j < 8; ++j) v[j] = ftile[(q * 8 + j) * LDT + og * 16 + lc];
    *(bf16x8*)(out + base + lane * 8) = v;
  }
}

// ---------------------------------------------------------------- combo96
// blocks 0..63: Wc frag tiles; 64..95: bias fold (32-way parallel).
__global__ __launch_bounds__(256) void combo96(
    const bf16* __restrict__ nW1at, const bf16* __restrict__ eW3b,
    short* __restrict__ Wcf, const float* __restrict__ eb3,
    const float* __restrict__ nb1, const float* __restrict__ nW1,
    float* __restrict__ bfold) {
  __shared__ short Al[64 * LDK];
  __shared__ short Bl[64 * LDK];
  __shared__ float red[256];
  const int bid = blockIdx.x;
  const int t = threadIdx.x;
  const int wid = t >> 6, lane = t & 63, q = lane >> 4, lc = lane & 15;
  const f32x4 zz = {0.f, 0.f, 0.f, 0.f};

  if (bid < 64) {
    const int wm = wid >> 1, wn = wid & 1;
    const int n0 = (bid >> 3) * 64, k0 = (bid & 7) * 64;
    f32x4 acc[2][2];
#pragma unroll
    for (int mb = 0; mb < 2; ++mb)
#pragma unroll
      for (int nb = 0; nb < 2; ++nb) acc[mb][nb] = zz;
    const int sr = t >> 2, seg = t & 3;
    for (int h0 = 0; h0 < 512; h0 += 32) {
      *(uint4*)&Al[sr * LDK + seg * 8] =
          *(const uint4*)(nW1at + (size_t)(n0 + sr) * 512 + h0 + seg * 8);
      *(uint4*)&Bl[sr * LDK + seg * 8] =
          *(const uint4*)(eW3b + (size_t)(k0 + sr) * 512 + h0 + seg * 8);
      __syncthreads();
      bf16x8 af[2], bfr[2];
#pragma unroll
      for (int mb = 0; mb < 2; ++mb)
        af[mb] = *(const bf16x8*)&Al[(wm * 32 + mb * 16 + lc) * LDK + q * 8];
#pragma unroll
      for (int nb = 0; nb < 2; ++nb)
        bfr[nb] = *(const bf16x8*)&Bl[(wn * 32 + nb * 16 + lc) * LDK + q * 8];
#pragma unroll
      for (int mb = 0; mb < 2; ++mb)
#pragma unroll
        for (int nb = 0; nb < 2; ++nb)
          acc[mb][nb] = mfma16(af[mb], bfr[nb], acc[mb][nb]);
      __syncthreads();
    }
#pragma unroll
    for (int mb = 0; mb < 2; ++mb)
#pragma unroll
      for (int nb = 0; nb < 2; ++nb)
#pragma unroll
        for (int r = 0; r < 4; ++r) {
          int n = n0 + wm * 32 + mb * 16 + q * 4 + r;
          int k = k0 + wn * 32 + nb * 16 + lc;
          int kt = k >> 5, kin = k & 31, qf = kin >> 3, jf = kin & 7;
          Wcf[(((size_t)kt * 32 + (n >> 4)) * 64 + qf * 16 + (n & 15)) * 8 +
              jf] = f2bf(acc[mb][nb][r]);
        }
    return;
  }
  {  // bias fold
    const int n = (bid - 64) * 16 + (t & 15);
    const int sl = t >> 4;
    float s = 0.f;
#pragma unroll 8
    for (int h = sl * 32; h < sl * 32 + 32; ++h)
      s += eb3[h] * nW1[(size_t)(132 + h) * 512 + n];
    red[sl * 16 + (t & 15)] = s;
    __syncthreads();
    if (t < 16) {
      float tot = 0.f;
#pragma unroll
      for (int k = 0; k < 16; ++k) tot += red[k * 16 + t];
      bfold[(bid - 64) * 16 + t] = nb1[(bid - 64) * 16 + t] + 15.f * tot;
    }
  }
}

// ---------------------------------------------------------------- mega
// One block = one batch. LDS (64,000 B, static):
//   [0]      PQL   16 x LDQ bf16 (33,024)   -> node: n1s 16 x LDN (overlay)
//   [33024]  sts   16 x 136 bf16 (4,352) / edge A-dbuf 2 x 64 x LDK (10,240)
//   [43264]  s_sum 64 x 8 f32 (2,048)
//   [45312]  s_sq  64 x 8 f32 (2,048)
//   [47360]  SL    16 x LDN bf16 (16,640)   -> total 64,000
__global__ __launch_bounds__(512, 4) void mega(
    const float* __restrict__ states, const int* __restrict__ action,
    const bf16* __restrict__ eW1f, const float* __restrict__ eb1,
    const bf16* __restrict__ eW2f, const float* __restrict__ eb2,
    const float* __restrict__ eg, const float* __restrict__ ebt,
    const bf16* __restrict__ nW1nf, const bf16* __restrict__ Wcf,
    const bf16* __restrict__ nW2f, const bf16* __restrict__ nW3f,
    const float* __restrict__ bfold, const float* __restrict__ nW1,
    const float* __restrict__ nb2, const float* __restrict__ ng,
    const float* __restrict__ nbt, const float* __restrict__ nb3,
    float* __restrict__ Out) {
  __shared__ __align__(16) char smem[64000];
  short* PQL = (short*)(smem);
  short* sts = (short*)(smem + 33024);
  short* Ab = (short*)(smem + 33024);  // edge phase overlay (2x2560 shorts)
  float* s_sum = (float*)(smem + 43264);
  float* s_sq = (float*)(smem + 45312);
  short* SL = (short*)(smem + 47360);
  short* n1s = PQL;  // node phase overlay

  const int t = threadIdx.x;
  const int w = t >> 6, lane = t & 63, q = lane >> 4, lc = lane & 15;
  const int bb = blockIdx.x;
  const f32x4 zz = {0.f, 0.f, 0.f, 0.f};

  // ---------------- phase 0: stage states [16][128] -> sts
  if (t < 256) {
    int r = t >> 4, c8 = (t & 15) * 8;
    *(bf16x8*)&sts[r * 136 + c8] =
        ld8f(states + ((size_t)bb * 16 + r) * 128 + c8);
  }
  __syncthreads();

  // ---------------- phase 1: PQ = [states@eW1_top + eb1 | states@eW1_bot]
  {
    f32x4 acc[8];
#pragma unroll
    for (int nb = 0; nb < 8; ++nb) acc[nb] = zz;
#pragma unroll
    for (int kt = 0; kt < 4; ++kt) {
      bf16x8 af = *(const bf16x8*)&sts[lc * 136 + kt * 32 + q * 8];
#pragma unroll
      for (int nb = 0; nb < 8; ++nb) {
        bf16x8 bfr = *(const bf16x8*)(eW1f +
                                      (((size_t)kt * 64 + w * 8 + nb) * 64 +
                                       lane) * 8);
        acc[nb] = mfma16(af, bfr, acc[nb]);
      }
    }
#pragma unroll
    for (int nb = 0; nb < 8; ++nb) {
      int col = w * 128 + nb * 16 + lc;
      float bv = (col < 512) ? eb1[col] : 0.f;
#pragma unroll
      for (int r = 0; r < 4; ++r)
        PQL[(q * 4 + r) * LDQ + col] = f2bf(acc[nb][r] + bv);
    }
  }
  __syncthreads();  // PQL ready; sts reads done (Ab may overwrite)

  // ---------------- phase 2: 4 edge tiles (r6 dbuf core), S -> SL
  const int ar = t >> 3;
  const int kk = (t & 7) * 4;
  const int gA = ar >> 4;
  const int slot = ar & 15;
  const bool padA = (slot == 15);
#pragma unroll 1
  for (int sg = 0; sg < 4; ++sg) {
    const int srcb = sg * 4 + gA;
    const int dstb = padA ? 0 : slot + (slot >= srcb ? 1 : 0);
    const short* pA = PQL + srcb * LDQ + kk;
    const short* qA = PQL + dstb * LDQ + 512 + kk;

    f32x4 acc[4][4];
#pragma unroll
    for (int mb = 0; mb < 4; ++mb)
#pragma unroll
      for (int nb = 0; nb < 4; ++nb) acc[mb][nb] = zz;

    auto buildA = [&](int kt, int buf) {
      short4v av = {0, 0, 0, 0};
      if (!padA) {
        short4v pv = *(const short4v*)(pA + kt * 32);
        short4v qv = *(const short4v*)(qA + kt * 32);
        av.x = f2bf(fmaxf(bs2f(pv.x) + bs2f(qv.x), 0.f));
        av.y = f2bf(fmaxf(bs2f(pv.y) + bs2f(qv.y), 0.f));
        av.z = f2bf(fmaxf(bs2f(pv.z) + bs2f(qv.z), 0.f));
        av.w = f2bf(fmaxf(bs2f(pv.w) + bs2f(qv.w), 0.f));
      }
      *(short4v*)&Ab[buf * 2560 + ar * LDK + kk] = av;
    };

    buildA(0, 0);
#pragma unroll 1
    for (int kt = 0; kt < 16; ++kt) {
      __syncthreads();
      const int cur = kt & 1;
      bf16x8 bfr[4], af[4];
#pragma unroll
      for (int nb = 0; nb < 4; ++nb)
        bfr[nb] = *(const bf16x8*)(eW2f +
                                   (((size_t)kt * 32 + w * 4 + nb) * 64 + lane) *
                                       8);
#pragma unroll
      for (int mb = 0; mb < 4; ++mb)
        af[mb] = *(const bf16x8*)&Ab[cur * 2560 + (mb * 16 + lc) * LDK + q * 8];
      if (kt < 15) buildA(kt + 1, cur ^ 1);
#pragma unroll
      for (int mb = 0; mb < 4; ++mb)
#pragma unroll
        for (int nb = 0; nb < 4; ++nb)
          acc[mb][nb] = mfma16(af[mb], bfr[nb], acc[mb][nb]);
    }

    // epilogue: +eb2, LN over 512 cols, relu, masked 15-row seg-sum -> SL
    float bv[4], gv[4], bev[4];
#pragma unroll
    for (int nb = 0; nb < 4; ++nb) {
      int col = w * 64 + nb * 16 + lc;
      bv[nb] = eb2[col];
      gv[nb] = eg[col];
      bev[nb] = ebt[col];
    }
#pragma unroll
    for (int mb = 0; mb < 4; ++mb)
#pragma unroll
      for (int nb = 0; nb < 4; ++nb)
#pragma unroll
        for (int r = 0; r < 4; ++r) acc[mb][nb][r] += bv[nb];

#pragma unroll
    for (int mb = 0; mb < 4; ++mb) {
      float ps[4] = {0, 0, 0, 0}, pq2[4] = {0, 0, 0, 0};
#pragma unroll
      for (int nb = 0; nb < 4; ++nb)
#pragma unroll
        for (int r = 0; r < 4; ++r) {
          float x = acc[mb][nb][r];
          ps[r] += x;
          pq2[r] += x * x;
        }
#pragma unroll
      for (int d = 1; d < 16; d <<= 1)
#pragma unroll
        for (int r = 0; r < 4; ++r) {
          ps[r] += __shfl_xor(ps[r], d, 64);
          pq2[r] += __shfl_xor(pq2[r], d, 64);
        }
      if (lc == 0)
#pragma unroll
        for (int r = 0; r < 4; ++r) {
          int row = mb * 16 + q * 4 + r;
          s_sum[row * 8 + w] = ps[r];
          s_sq[row * 8 + w] = pq2[r];
        }
    }
    __syncthreads();
#pragma unroll
    for (int mb = 0; mb < 4; ++mb) {
      float sv[4] = {0, 0, 0, 0};
#pragma unroll
      for (int r = 0; r < 4; ++r) {
        int row = mb * 16 + q * 4 + r;
        float tot = 0.f, tsq = 0.f;
#pragma unroll
        for (int wv = 0; wv < 8; ++wv) {
          tot += s_sum[row * 8 + wv];
          tsq += s_sq[row * 8 + wv];
        }
        float m = tot * (1.f / 512.f);
        float rstd = rsqrtf(tsq * (1.f / 512.f) - m * m + 1e-5f);
#pragma unroll
        for (int nb = 0; nb < 4; ++nb) {
          float h = (acc[mb][nb][r] - m) * rstd * gv[nb] + bev[nb];
          h = fmaxf(h, 0.f);
          if (q * 4 + r != 15) sv[nb] += h;
        }
      }
#pragma unroll
      for (int nb = 0; nb < 4; ++nb) {
        sv[nb] += __shfl_xor(sv[nb], 16, 64);
        sv[nb] += __shfl_xor(sv[nb], 32, 64);
      }
      if (lane < 16)
#pragma unroll
        for (int nb = 0; nb < 4; ++nb)
          SL[(sg * 4 + mb) * LDN + w * 64 + nb * 16 + lc] = f2bf(sv[nb]);
    }
    __syncthreads();  // stats/SL safe; next tile may rebuild Ab
  }

  // ---------------- phase 3: node MLP (8 waves, 64 cols each)
  // re-stage states (Ab overwrote sts during edge)
  if (t < 256) {
    int r = t >> 4, c8 = (t & 15) * 8;
    *(bf16x8*)&sts[r * 136 + c8] =
        ld8f(states + ((size_t)bb * 16 + r) * 128 + c8);
  }
  __syncthreads();

  {  // phase A: n1 = relu(states@nW1n + onehot + S@Wc + bfold) -> n1s
    f32x4 acc[4];
#pragma unroll
    for (int nb = 0; nb < 4; ++nb) acc[nb] = zz;
#pragma unroll
    for (int kt = 0; kt < 4; ++kt) {
      bf16x8 af = *(const bf16x8*)&sts[lc * 136 + kt * 32 + q * 8];
#pragma unroll
      for (int nb = 0; nb < 4; ++nb) {
        bf16x8 bfr = *(const bf16x8*)(nW1nf +
                                      (((size_t)kt * 32 + w * 4 + nb) * 64 +
                                       lane) * 8);
        acc[nb] = mfma16(af, bfr, acc[nb]);
      }
    }
#pragma unroll 2
    for (int kt = 0; kt < 16; ++kt) {
      bf16x8 af = *(const bf16x8*)&SL[lc * LDN + kt * 32 + q * 8];
#pragma unroll
      for (int nb = 0; nb < 4; ++nb) {
        bf16x8 bfr = *(const bf16x8*)(Wcf +
                                      (((size_t)kt * 32 + w * 4 + nb) * 64 +
                                       lane) * 8);
        acc[nb] = mfma16(af, bfr, acc[nb]);
      }
    }
    int a = action[bb];
    int aw = a >> 2, ac4 = a & 3;
#pragma unroll
    for (int nb = 0; nb < 4; ++nb) {
      int col = w * 64 + nb * 16 + lc;
      float bv = bfold[col];
      float awv = nW1[(size_t)(128 + ac4) * 512 + col];
#pragma unroll
      for (int r = 0; r < 4; ++r) {
        int row = q * 4 + r;
        float x = acc[nb][r] + bv + (row == aw ? awv : 0.f);
        n1s[row * LDN + col] = f2bf(fmaxf(x, 0.f));
      }
    }
  }
  __syncthreads();

  {  // phase B: n2 = relu(LN(n1@nW2 + nb2)) -> n1s
    f32x4 acc[4];
#pragma unroll
    for (int nb = 0; nb < 4; ++nb) acc[nb] = zz;
#pragma unroll 2
    for (int kt = 0; kt < 16; ++kt) {
      bf16x8 af = *(const bf16x8*)&n1s[lc * LDN + kt * 32 + q * 8];
#pragma unroll
      for (int nb = 0; nb < 4; ++nb) {
        bf16x8 bfr = *(const bf16x8*)(nW2f +
                                      (((size_t)kt * 32 + w * 4 + nb) * 64 +
                                       lane) * 8);
        acc[nb] = mfma16(af, bfr, acc[nb]);
      }
    }
    float gv[4], bev[4];
    float ps[4] = {0, 0, 0, 0}, pq2[4] = {0, 0, 0, 0};
#pragma unroll
    for (int nb = 0; nb < 4; ++nb) {
      int col = w * 64 + nb * 16 + lc;
      float bv = nb2[col];
      gv[nb] = ng[col];
      bev[nb] = nbt[col];
#pragma unroll
      for (int r = 0; r < 4; ++r) {
        acc[nb][r] += bv;
        ps[r] += acc[nb][r];
        pq2[r] += acc[nb][r] * acc[nb][r];
      }
    }
#pragma unroll
    for (int d = 1; d < 16; d <<= 1)
#pragma unroll
      for (int r = 0; r < 4; ++r) {
        ps[r] += __shfl_xor(ps[r], d, 64);
        pq2[r] += __shfl_xor(pq2[r], d, 64);
      }
    if (lc == 0)
#pragma unroll
      for (int r = 0; r < 4; ++r) {
        s_sum[(q * 4 + r) * 8 + w] = ps[r];
        s_sq[(q * 4 + r) * 8 + w] = pq2[r];
      }
    __syncthreads();  // all MFMA reads of n1s done too
#pragma unroll
    for (int r = 0; r < 4; ++r) {
      int row = q * 4 + r;
      float tot = 0.f, tsq = 0.f;
#pragma unroll
      for (int wv = 0; wv < 8; ++wv) {
        tot += s_sum[row * 8 + wv];
        tsq += s_sq[row * 8 + wv];
      }
      float m = tot * (1.f / 512.f);
      float rstd = rsqrtf(tsq * (1.f / 512.f) - m * m + 1e-5f);
#pragma unroll
      for (int nb = 0; nb < 4; ++nb) {
        int col = w * 64 + nb * 16 + lc;
        float h = (acc[nb][r] - m) * rstd * gv[nb] + bev[nb];
        n1s[row * LDN + col] = f2bf(fmaxf(h, 0.f));
      }
    }
  }
  __syncthreads();

  {  // phase C: out = n2@nW3 + nb3 (wave w -> cols w*16..w*16+16)
    f32x4 acc3 = zz;
#pragma unroll 2
    for (int kt = 0; kt < 16; ++kt) {
      bf16x8 af = *(const bf16x8*)&n1s[lc * LDN + kt * 32 + q * 8];
      bf16x8 bfr = *(const bf16x8*)(nW3f +
                                    (((size_t)kt * 8 + w) * 64 + lane) * 8);
      acc3 = mfma16(af, bfr, acc3);
    }
    int col = w * 16 + lc;
    float b3 = nb3[col];
#pragma unroll
    for (int r = 0; r < 4; ++r)
      Out[((size_t)bb * 16 + q * 4 + r) * 128 + col] = acc3[r] + b3;
  }
}

// ---------------------------------------------------------------- launch
extern "C" void kernel_launch(void* const* d_in, const int* in_sizes, int n_in,
                              void* d_out, int out_size, void* d_ws,
                              size_t ws_size, hipStream_t stream) {
  const float* states = (const float*)d_in[0];
  const int* action = (const int*)d_in[1];
  const float* eW1 = (const float*)d_in[2];
  const float* eb1 = (const float*)d_in[3];
  const float* eW2 = (const float*)d_in[4];
  const float* eb2 = (const float*)d_in[5];
  const float* eg = (const float*)d_in[6];
  const float* ebt = (const float*)d_in[7];
  const float* eW3 = (const float*)d_in[8];
  const float* eb3 = (const float*)d_in[9];
  const float* nW1 = (const float*)d_in[10];
  const float* nb1 = (const float*)d_in[11];
  const float* nW2 = (const float*)d_in[12];
  const float* nb2 = (const float*)d_in[13];
  const float* ng = (const float*)d_in[14];
  const float* nbt = (const float*)d_in[15];
  const float* nW3 = (const float*)d_in[16];
  const float* nb3 = (const float*)d_in[17];

  // ---- workspace: weights only (~5.3 MB)
  char* w = (char*)d_ws;
  bf16* eW1f = (bf16*)w;     w += (size_t)131072 * 2;
  bf16* eW2f = (bf16*)w;     w += (size_t)262144 * 2;
  bf16* nW1nf = (bf16*)w;    w += (size_t)65536 * 2;
  bf16* nW2f = (bf16*)w;     w += (size_t)262144 * 2;
  bf16* nW3f = (bf16*)w;     w += (size_t)65536 * 2;
  bf16* Wcf = (bf16*)w;      w += (size_t)262144 * 2;
  bf16* eW3b = (bf16*)w;     w += (size_t)262144 * 2;
  bf16* nW1at = (bf16*)w;    w += (size_t)262144 * 2;
  float* bfold = (float*)w;  w += (size_t)512 * 4;

  mega_prep<<<dim3(256, 1, 8), 256, 0, stream>>>(
      eW3, (short*)eW3b, nW1, (unsigned short*)nW1at, eW1, (short*)eW1f, eW2,
      (short*)eW2f, (short*)nW1nf, nW2, (short*)nW2f, nW3, (short*)nW3f);

  combo96<<<96, 256, 0, stream>>>(nW1at, eW3b, (short*)Wcf, eb3, nb1, nW1,
                                  bfold);

  mega<<<512, 512, 0, stream>>>(states, action, eW1f, eb1, eW2f, eb2, eg, ebt,
                                nW1nf, Wcf, nW2f, nW3f, bfold, nW1, nb2, ng,
                                nbt, nb3, (float*)d_out);

  (void)in_sizes; (void)n_in; (void)out_size; (void)ws_size;
}